// Round 2
// baseline (115.812 us; speedup 1.0000x reference)
//
#include <hip/hip_runtime.h>
#include <math.h>

// Problem constants (from reference setup_inputs): b=64, seq=2048, hid=256
#define BATCH 64
#define SEQ   2048
#define HID   256
#define KNEG  63            // b - 1

// loss denominator: b*200*(K+1)*4 = 64*200*64*4 = 3,276,800
#define INV_DENOM (1.0f / 3276800.0f)

__device__ __forceinline__ float dot4(const float4& u, const float4& v) {
  return u.x * v.x + u.y * v.y + u.z * v.z + u.w * v.w;
}
__device__ __forceinline__ void fma4(float4& acc, const float4& v, float s) {
  acc.x = fmaf(v.x, s, acc.x);
  acc.y = fmaf(v.y, s, acc.y);
  acc.z = fmaf(v.z, s, acc.z);
  acc.w = fmaf(v.w, s, acc.w);
}

// Block s computes (math identical to R1, verified absmax 0.0):
//   D[s]  = sum_i <rs_n[i,s], rt_n[i,s]>
//   S[s]  = sum_i rs_n[i,s,:],  T[s] = sum_i rt_n[i,s,:]
//   partial[s] = (2*b - (1.5 + 1/(2K))*D + <S,T>/(2K)) / denom
// then the last block to finish reduces partial[] -> out (deterministic
// fixed-order sum by one block).
//
// Layout: 4 waves; each wave owns 16 batch rows, processed 4-at-a-time.
// Within a wave, 16-lane group g handles one row; lane (g,k) covers hid
// elements {c*64 + k*4 .. +3 | c=0..3}. Row reductions need only a 4-step
// butterfly over 16 lanes (offsets 1,2,4,8) instead of 6 steps over 64.
__global__ __launch_bounds__(256) void cosnce_fused(
    const float* __restrict__ rs, const float* __restrict__ rt,
    float* __restrict__ partial, unsigned int* __restrict__ counter,
    float* __restrict__ out) {
  const int s    = blockIdx.x;      // 0..SEQ-1
  const int tid  = threadIdx.x;     // 0..255
  const int wave = tid >> 6;        // 0..3
  const int lane = tid & 63;        // 0..63
  const int g    = lane >> 4;       // 0..3  (row group within wave)
  const int k    = lane & 15;       // 0..15 (sublane within group)

  float4 Sacc0 = make_float4(0.f, 0.f, 0.f, 0.f), Sacc1 = Sacc0, Sacc2 = Sacc0, Sacc3 = Sacc0;
  float4 Tacc0 = Sacc0, Tacc1 = Sacc0, Tacc2 = Sacc0, Tacc3 = Sacc0;
  float  Dacc  = 0.f;

#pragma unroll
  for (int r = 0; r < 4; ++r) {
    const int    i    = wave * 16 + r * 4 + g;
    const size_t base = ((size_t)i * SEQ + s) * HID + k * 4;
    const float* pa   = rs + base;
    const float* pb   = rt + base;
    // 8 independent 16B loads (4 chunks x 2 inputs) -> good MLP
    const float4 a0 = *(const float4*)(pa);
    const float4 a1 = *(const float4*)(pa + 64);
    const float4 a2 = *(const float4*)(pa + 128);
    const float4 a3 = *(const float4*)(pa + 192);
    const float4 b0 = *(const float4*)(pb);
    const float4 b1 = *(const float4*)(pb + 64);
    const float4 b2 = *(const float4*)(pb + 128);
    const float4 b3 = *(const float4*)(pb + 192);

    float ss = dot4(a0, a0) + dot4(a1, a1) + dot4(a2, a2) + dot4(a3, a3);
    float tt = dot4(b0, b0) + dot4(b1, b1) + dot4(b2, b2) + dot4(b3, b3);
    float st = dot4(a0, b0) + dot4(a1, b1) + dot4(a2, b2) + dot4(a3, b3);

    // 4-step butterfly within the 16-lane group (xor keeps lanes in-group)
#pragma unroll
    for (int off = 1; off <= 8; off <<= 1) {
      ss += __shfl_xor(ss, off);
      tt += __shfl_xor(tt, off);
      st += __shfl_xor(st, off);
    }

    // F.normalize: x / max(||x||, 1e-12)  ->  rsq(max(ss, 1e-24))
    const float inv_s = __builtin_amdgcn_rsqf(fmaxf(ss, 1e-24f));
    const float inv_t = __builtin_amdgcn_rsqf(fmaxf(tt, 1e-24f));

    Dacc = fmaf(st, inv_s * inv_t, Dacc);
    fma4(Sacc0, a0, inv_s); fma4(Sacc1, a1, inv_s);
    fma4(Sacc2, a2, inv_s); fma4(Sacc3, a3, inv_s);
    fma4(Tacc0, b0, inv_t); fma4(Tacc1, b1, inv_t);
    fma4(Tacc2, b2, inv_t); fma4(Tacc3, b3, inv_t);
  }

  // Cross-group reduce within the wave: groups g=0..3 hold the SAME hid
  // elements (for different rows), so xor-16/xor-32 sums them. Once per kernel.
#pragma unroll
  for (int off = 16; off <= 32; off <<= 1) {
    Sacc0.x += __shfl_xor(Sacc0.x, off); Sacc0.y += __shfl_xor(Sacc0.y, off);
    Sacc0.z += __shfl_xor(Sacc0.z, off); Sacc0.w += __shfl_xor(Sacc0.w, off);
    Sacc1.x += __shfl_xor(Sacc1.x, off); Sacc1.y += __shfl_xor(Sacc1.y, off);
    Sacc1.z += __shfl_xor(Sacc1.z, off); Sacc1.w += __shfl_xor(Sacc1.w, off);
    Sacc2.x += __shfl_xor(Sacc2.x, off); Sacc2.y += __shfl_xor(Sacc2.y, off);
    Sacc2.z += __shfl_xor(Sacc2.z, off); Sacc2.w += __shfl_xor(Sacc2.w, off);
    Sacc3.x += __shfl_xor(Sacc3.x, off); Sacc3.y += __shfl_xor(Sacc3.y, off);
    Sacc3.z += __shfl_xor(Sacc3.z, off); Sacc3.w += __shfl_xor(Sacc3.w, off);
    Tacc0.x += __shfl_xor(Tacc0.x, off); Tacc0.y += __shfl_xor(Tacc0.y, off);
    Tacc0.z += __shfl_xor(Tacc0.z, off); Tacc0.w += __shfl_xor(Tacc0.w, off);
    Tacc1.x += __shfl_xor(Tacc1.x, off); Tacc1.y += __shfl_xor(Tacc1.y, off);
    Tacc1.z += __shfl_xor(Tacc1.z, off); Tacc1.w += __shfl_xor(Tacc1.w, off);
    Tacc2.x += __shfl_xor(Tacc2.x, off); Tacc2.y += __shfl_xor(Tacc2.y, off);
    Tacc2.z += __shfl_xor(Tacc2.z, off); Tacc2.w += __shfl_xor(Tacc2.w, off);
    Tacc3.x += __shfl_xor(Tacc3.x, off); Tacc3.y += __shfl_xor(Tacc3.y, off);
    Tacc3.z += __shfl_xor(Tacc3.z, off); Tacc3.w += __shfl_xor(Tacc3.w, off);
    Dacc += __shfl_xor(Dacc, off);
  }

  __shared__ float S_sh[4][HID];
  __shared__ float T_sh[4][HID];
  __shared__ float D_sh[4];
  __shared__ float red_sh[4];
  __shared__ unsigned int done_sh;

  if (g == 0) {
    // lane k holds elements c*64 + k*4 .. +3
    *(float4*)&S_sh[wave][0 * 64 + k * 4] = Sacc0;
    *(float4*)&S_sh[wave][1 * 64 + k * 4] = Sacc1;
    *(float4*)&S_sh[wave][2 * 64 + k * 4] = Sacc2;
    *(float4*)&S_sh[wave][3 * 64 + k * 4] = Sacc3;
    *(float4*)&T_sh[wave][0 * 64 + k * 4] = Tacc0;
    *(float4*)&T_sh[wave][1 * 64 + k * 4] = Tacc1;
    *(float4*)&T_sh[wave][2 * 64 + k * 4] = Tacc2;
    *(float4*)&T_sh[wave][3 * 64 + k * 4] = Tacc3;
    if (k == 0) D_sh[wave] = Dacc;
  }
  __syncthreads();

  // thread t combines hid element t across waves; block-reduce <S,T>
  float Ssum = S_sh[0][tid] + S_sh[1][tid] + S_sh[2][tid] + S_sh[3][tid];
  float Tsum = T_sh[0][tid] + T_sh[1][tid] + T_sh[2][tid] + T_sh[3][tid];
  float prod = Ssum * Tsum;
#pragma unroll
  for (int off = 32; off > 0; off >>= 1) prod += __shfl_xor(prod, off);
  if (lane == 0) red_sh[wave] = prod;
  __syncthreads();

  if (tid == 0) {
    const float STdot = red_sh[0] + red_sh[1] + red_sh[2] + red_sh[3];
    const float Dtot  = D_sh[0] + D_sh[1] + D_sh[2] + D_sh[3];
    const float inv2K = 1.f / (2.f * (float)KNEG);
    const float cres  = 2.f * (float)BATCH - (1.5f + inv2K) * Dtot + STdot * inv2K;
    partial[s] = cres * INV_DENOM;
    __threadfence();                        // release partial[s] device-wide
    done_sh = atomicAdd(counter, 1u);       // signal completion
  }
  __syncthreads();

  // Last block to finish does the (deterministic, fixed-order) final sum.
  if (done_sh == SEQ - 1) {
    __threadfence();                        // acquire: see all partial[] writes
    float acc = 0.f;
    for (int idx = tid; idx < SEQ; idx += 256) acc += partial[idx];
#pragma unroll
    for (int off = 32; off > 0; off >>= 1) acc += __shfl_xor(acc, off);
    if (lane == 0) red_sh[wave] = acc;      // safe: barrier above ordered prior use
    __syncthreads();
    if (tid == 0) out[0] = red_sh[0] + red_sh[1] + red_sh[2] + red_sh[3];
  }
}

extern "C" void kernel_launch(void* const* d_in, const int* in_sizes, int n_in,
                              void* d_out, int out_size, void* d_ws, size_t ws_size,
                              hipStream_t stream) {
  const float* rs = (const float*)d_in[0];   // r_s [64,2048,256] fp32
  const float* rt = (const float*)d_in[1];   // r_t [64,2048,256] fp32
  float* out      = (float*)d_out;           // scalar fp32 loss
  float* partial  = (float*)d_ws;            // SEQ floats
  unsigned int* counter = (unsigned int*)((char*)d_ws + SEQ * sizeof(float));

  // counter must start at 0 every call (ws is poisoned 0xAA once, never reset)
  hipMemsetAsync(counter, 0, sizeof(unsigned int), stream);
  cosnce_fused<<<SEQ, 256, 0, stream>>>(rs, rt, partial, counter, out);
}